// Round 1
// 387.373 us; speedup vs baseline: 1.0086x; 1.0086x over previous
//
#include <hip/hip_runtime.h>
#include <math.h>

#define NO_LAYERS 2048
#define MODES 4096
#define APL 8
#define OUT_N (NO_LAYERS * APL)   // 16384

// Native clang vector type — required by __builtin_nontemporal_load
// (HIP's float4 class is rejected by the builtin's type check).
typedef float nf4 __attribute__((ext_vector_type(4)));

// Re(tanh(t*(Sr+i*Si))), numerically stable for |t*Sr| up to thousands.
// Re tanh(x+iy) = sinh(2x)/(cosh(2x)+cos(2y))
//              = sign(x)*(1-e^{-2a}) / (1+e^{-2a}+2 e^{-a} cos(2y)),  a=2|x|
__device__ __forceinline__ float retanh_cplx(float t, float Sr, float Si) {
    float x = t * Sr;
    float y = t * Si;
    float a = 2.0f * fabsf(x);
    float e1 = expf(-a);          // 0 for a > ~88 (saturated regime)
    float e2 = e1 * e1;
    float num = 1.0f - e2;
    float den = 1.0f + e2 + 2.0f * e1 * cosf(2.0f * y);
    return copysignf(num / den, x);
}

// FUSED prep + lin1 (R1): the old 8-block k_prep serialized ~10 us of
// latency-bound work ahead of the whole pipeline. Its result t[2048] is
// cheap to recompute per block: S0..S2 are sums over 96 KB of w_fft
// (L2-resident after the first blocks touch it) and t is 24 transcendental
// ops/thread of pure VALU work that overlaps with the NT weight stream.
// The 8 NT weight loads per lane are issued FIRST (they do not depend on t),
// so the 32 MB weight stream is in flight while the block computes S and t.
__global__ void __launch_bounds__(256) k_lin1f(const float* __restrict__ model_p,
                                               const float* __restrict__ w0,
                                               const float* __restrict__ w1,
                                               const float* __restrict__ w2,
                                               const float* __restrict__ w,
                                               const float* __restrict__ b,
                                               float* __restrict__ h) {
    __shared__ float red[3][2][4];
    __shared__ float S[3][2];
    __shared__ float ts[NO_LAYERS];          // 8 KB
    const int tid = threadIdx.x;             // 0..255
    const int wave = tid >> 6, lane = tid & 63;

    // ---- issue the read-once weight stream immediately (no deps) ----
    const int row = blockIdx.x * 4 + wave;   // < 4096
    const nf4* wp = (const nf4*)(w + (size_t)row * NO_LAYERS);
    nf4 wv[(NO_LAYERS / 4) / 64];            // 8 x 16B = 32 VGPRs
    #pragma unroll
    for (int i = 0; i < (NO_LAYERS / 4) / 64; i++)
        wv[i] = __builtin_nontemporal_load(&wp[i * 64 + lane]);

    // ---- S0..S2: complex sums of w_fft (cached loads: reused by all blocks) ----
    const float* wptr[3] = {w0, w1, w2};
    float sr[3] = {0.f, 0.f, 0.f}, si[3] = {0.f, 0.f, 0.f};
    #pragma unroll
    for (int q = 0; q < 3; q++) {
        const float2* p = (const float2*)wptr[q];   // interleaved re,im
        #pragma unroll
        for (int i = 0; i < MODES / 256; i++) {     // 16 iters
            float2 v = p[i * 256 + tid];
            sr[q] += v.x; si[q] += v.y;
        }
    }
    #pragma unroll
    for (int off = 32; off > 0; off >>= 1) {
        #pragma unroll
        for (int q = 0; q < 3; q++) {
            sr[q] += __shfl_down(sr[q], off);
            si[q] += __shfl_down(si[q], off);
        }
    }
    if (lane == 0) {
        #pragma unroll
        for (int q = 0; q < 3; q++) { red[q][0][wave] = sr[q]; red[q][1][wave] = si[q]; }
    }
    __syncthreads();
    if (tid < 6) {
        int q = tid >> 1, c = tid & 1;
        S[q][c] = red[q][c][0] + red[q][c][1] + red[q][c][2] + red[q][c][3];
    }
    __syncthreads();
    const float S0r = S[0][0], S0i = S[0][1];
    const float S1r = S[1][0], S1i = S[1][1];
    const float S2r = S[2][0], S2i = S[2][1];

    // ---- t[2048]: one strided model_p column read (L2-hot after block 0)
    //      + 3 chained complex tanh per element ----
    #pragma unroll
    for (int k = 0; k < NO_LAYERS / 256; k++) {      // 8 iters
        const int f = k * 256 + tid;
        float t = model_p[(size_t)f * MODES];        // column 0 of model_p
        t = retanh_cplx(t, S0r, S0i);
        t = retanh_cplx(t, S1r, S1i);
        t = retanh_cplx(t, S2r, S2i);
        ts[f] = t;
    }
    __syncthreads();

    // ---- lin1 row dot from LDS; weights already in registers ----
    const float4* tp = (const float4*)ts;
    float acc = 0.f;
    #pragma unroll
    for (int i = 0; i < (NO_LAYERS / 4) / 64; i++) {   // 8 iters
        float4 tv = tp[i * 64 + lane];
        acc += wv[i].x * tv.x + wv[i].y * tv.y + wv[i].z * tv.z + wv[i].w * tv.w;
    }
    #pragma unroll
    for (int off = 32; off > 0; off >>= 1) acc += __shfl_down(acc, off);
    if (lane == 0) h[row] = tanhf(acc + b[row]);
}

// out[j] = dot(h, lin2_w[j,:]) + b[j];  lin2_w: (16384, 4096) row-major.
// Two rows per wave, h staged in LDS, streaming weights non-temporal
// (read-once 268 MB stream — bypassing L2/L3 avoids cache churn, measured
// in a prior session: NT ~17 us faster). R1: the first 4 weight iterations
// per row are prefetched into registers BEFORE the h->LDS staging barrier,
// so the weight stream starts at block launch instead of after the barrier.
__global__ void __launch_bounds__(256) k_lin2(const float* __restrict__ h,
                                              const float* __restrict__ w,
                                              const float* __restrict__ b,
                                              float* __restrict__ out) {
    __shared__ float hs[MODES];              // 16 KB
    const int tid = threadIdx.x;
    const int wave = tid >> 6, lane = tid & 63;
    const int row0 = blockIdx.x * 8 + wave * 2;   // 2048 blocks * 8 rows = 16384
    const nf4* wp0 = (const nf4*)(w + (size_t)row0 * MODES);
    const nf4* wp1 = (const nf4*)(w + (size_t)(row0 + 1) * MODES);

    // prefetch first 4 iterations of both weight rows (8 x 16B = 32 VGPRs)
    nf4 pw0[4], pw1[4];
    #pragma unroll
    for (int i = 0; i < 4; i++) {
        pw0[i] = __builtin_nontemporal_load(&wp0[i * 64 + lane]);
        pw1[i] = __builtin_nontemporal_load(&wp1[i * 64 + lane]);
    }

    {   // stage h (16 KB) to LDS
        const float4* hp = (const float4*)h;
        float4* sp = (float4*)hs;
        #pragma unroll
        for (int i = 0; i < (MODES / 4) / 256; i++) sp[i * 256 + tid] = hp[i * 256 + tid];
    }
    __syncthreads();

    const float4* hp = (const float4*)hs;
    float acc0 = 0.f, acc1 = 0.f;
    #pragma unroll
    for (int i = 0; i < 4; i++) {                     // prefetched head
        float4 hv = hp[i * 64 + lane];
        acc0 += pw0[i].x * hv.x + pw0[i].y * hv.y + pw0[i].z * hv.z + pw0[i].w * hv.w;
        acc1 += pw1[i].x * hv.x + pw1[i].y * hv.y + pw1[i].z * hv.z + pw1[i].w * hv.w;
    }
    #pragma unroll
    for (int i = 4; i < (MODES / 4) / 64; i++) {      // 12 streamed iters
        const int idx = i * 64 + lane;
        float4 hv = hp[idx];
        nf4 w0v = __builtin_nontemporal_load(&wp0[idx]);
        nf4 w1v = __builtin_nontemporal_load(&wp1[idx]);
        acc0 += w0v.x * hv.x + w0v.y * hv.y + w0v.z * hv.z + w0v.w * hv.w;
        acc1 += w1v.x * hv.x + w1v.y * hv.y + w1v.z * hv.z + w1v.w * hv.w;
    }
    #pragma unroll
    for (int off = 32; off > 0; off >>= 1) {
        acc0 += __shfl_down(acc0, off);
        acc1 += __shfl_down(acc1, off);
    }
    if (lane == 0) {
        out[row0]     = acc0 + b[row0];
        out[row0 + 1] = acc1 + b[row0 + 1];
    }
}

extern "C" void kernel_launch(void* const* d_in, const int* in_sizes, int n_in,
                              void* d_out, int out_size, void* d_ws, size_t ws_size,
                              hipStream_t stream) {
    const float* model_p = (const float*)d_in[0];
    const float* w0      = (const float*)d_in[1];   // complex64 interleaved
    const float* w1      = (const float*)d_in[2];
    const float* w2      = (const float*)d_in[3];
    const float* lin1_w  = (const float*)d_in[4];
    const float* lin1_b  = (const float*)d_in[5];
    const float* lin2_w  = (const float*)d_in[6];
    const float* lin2_b  = (const float*)d_in[7];
    float* out = (float*)d_out;

    float* h = (float*)d_ws;          // 4096 floats

    k_lin1f<<<1024, 256, 0, stream>>>(model_p, w0, w1, w2, lin1_w, lin1_b, h);
    k_lin2<<<2048, 256, 0, stream>>>(h, lin2_w, lin2_b, out);
}